// Round 1
// baseline (1108.054 us; speedup 1.0000x reference)
//
#include <hip/hip_runtime.h>
#include <hip/hip_bf16.h>
#include <math.h>

#define NPIX    16384
#define OBSD    768
#define OBJ     128
#define NS      32
#define HIDD    256
#define RELD    64
#define ACTD    16
#define QSCALE  0.08838834764831845f   /* 128^-0.5 */
#define LNEPS   1e-5f
#define ATEPS   1e-8f
#define DTC     0.1f

/* ---- workspace layout (floats) ---- */
#define OFF_STATS 0                         /* 16384*2          */
#define OFF_KV    (OFF_STATS + NPIX*2)      /* 16384*256        */
#define OFF_SLOTS (OFF_KV + NPIX*256)       /* 4096             */
#define OFF_Q     (OFF_SLOTS + 4096)        /* 4096             */
#define OFF_H     (OFF_Q + 4096)            /* 4096             */
#define OFF_APART (OFF_H + 4096)            /* 256*4128         */
#define OFF_OBJ   (OFF_APART + 256*4128)    /* 4096             */
#define OFF_FEAT  (OFF_OBJ + 4096)          /* 4096 + 65536     */
#define OFF_P1    (OFF_FEAT + 69632)        /* 1024*1536        */
#define OFF_HREND (OFF_P1 + 1024*1536)      /* 1536             */
#define OFF_P3    (OFF_HREND + 1536)        /* 48*768           */

/* ================= LN stats: mean/rstd per pixel row ================= */
__global__ __launch_bounds__(256) void k_stats(const float* __restrict__ obs,
                                               float* __restrict__ stats)
{
    int lane = threadIdx.x & 63;
    int w    = threadIdx.x >> 6;
    int row  = blockIdx.x * 4 + w;
    const float* o = obs + (size_t)row * OBSD;
    float s = 0.f, s2 = 0.f;
    #pragma unroll
    for (int i = 0; i < 12; ++i) { float v = o[lane + 64*i]; s += v; s2 += v*v; }
    #pragma unroll
    for (int off = 32; off > 0; off >>= 1) {
        s  += __shfl_down(s,  off);
        s2 += __shfl_down(s2, off);
    }
    if (lane == 0) {
        float m   = s  * (1.f/OBSD);
        float var = s2 * (1.f/OBSD) - m*m;
        stats[row*2]   = m;
        stats[row*2+1] = rsqrtf(var + LNEPS);
    }
}

/* ====== kv GEMM: x_ln(16384x768) @ [Wk|Wv](768x256) -> kv[n][256] ====== */
#define STA 129
__global__ __launch_bounds__(256) void k_kv(
    const float* __restrict__ obs, const float* __restrict__ stats,
    const float* __restrict__ g, const float* __restrict__ b,
    const float* __restrict__ Wk, const float* __restrict__ Wv,
    float* __restrict__ kv)
{
    __shared__ float As[32*STA];   /* [kk][m], padded */
    __shared__ float Bs[32*128];   /* [kk][jj]        */
    __shared__ float sm[128], sr[128];
    int t  = threadIdx.x;
    int m0 = blockIdx.x * 128;
    int nsel = blockIdx.y;
    const float* W = nsel ? Wv : Wk;
    int tx = t & 15, ty = t >> 4;
    float acc[8][8];
    #pragma unroll
    for (int i = 0; i < 8; ++i) {
        #pragma unroll
        for (int j = 0; j < 8; ++j) acc[i][j] = 0.f;
    }
    if (t < 128) { sm[t] = stats[(m0+t)*2]; sr[t] = stats[(m0+t)*2+1]; }

    for (int ks = 0; ks < 24; ++ks) {
        int k0 = ks * 32;
        __syncthreads();
        #pragma unroll
        for (int r = 0; r < 16; ++r) {          /* A: 128m x 32kk */
            int id = t + 256*r;
            int m  = id >> 5, kk = id & 31;
            float val = obs[(size_t)(m0+m)*OBSD + k0 + kk];
            val = (val - sm[m]) * sr[m] * g[k0+kk] + b[k0+kk];
            As[kk*STA + m] = val;
        }
        #pragma unroll
        for (int r = 0; r < 16; ++r) {          /* B: 32kk x 128jj */
            int id = t + 256*r;
            int kk = id >> 7, jj = id & 127;
            Bs[kk*128 + jj] = W[(size_t)(k0+kk)*128 + jj];
        }
        __syncthreads();
        #pragma unroll
        for (int kk = 0; kk < 32; ++kk) {
            float a8[8], b8[8];
            #pragma unroll
            for (int i = 0; i < 8; ++i) a8[i] = As[kk*STA + ty*8 + i];
            float4 u0 = *(const float4*)&Bs[kk*128 + tx*8];
            float4 u1 = *(const float4*)&Bs[kk*128 + tx*8 + 4];
            b8[0]=u0.x; b8[1]=u0.y; b8[2]=u0.z; b8[3]=u0.w;
            b8[4]=u1.x; b8[5]=u1.y; b8[6]=u1.z; b8[7]=u1.w;
            #pragma unroll
            for (int i = 0; i < 8; ++i) {
                #pragma unroll
                for (int j = 0; j < 8; ++j)
                    acc[i][j] = fmaf(a8[i], b8[j], acc[i][j]);
            }
        }
    }
    #pragma unroll
    for (int i = 0; i < 8; ++i) {
        size_t row = (size_t)(m0 + ty*8 + i);
        float4 o0 = make_float4(acc[i][0], acc[i][1], acc[i][2], acc[i][3]);
        float4 o1 = make_float4(acc[i][4], acc[i][5], acc[i][6], acc[i][7]);
        *(float4*)&kv[row*256 + nsel*128 + tx*8]     = o0;
        *(float4*)&kv[row*256 + nsel*128 + tx*8 + 4] = o1;
    }
}

/* ================= slot init ================= */
__global__ __launch_bounds__(256) void k_slots_init(
    const float* __restrict__ mu, const float* __restrict__ lsig,
    const float* __restrict__ noise, float* __restrict__ slots)
{
    int id = blockIdx.x * 256 + threadIdx.x;
    int d  = id & 127;
    slots[id] = mu[d] + expf(lsig[d]) * noise[id];
}

/* ================= q = LN(slots) @ Wq ================= */
__global__ __launch_bounds__(128) void k_q(
    const float* __restrict__ slots, const float* __restrict__ Wq,
    const float* __restrict__ g, const float* __restrict__ b,
    float* __restrict__ qg)
{
    int s = blockIdx.x, t = threadIdx.x;
    float x = slots[s*128 + t];
    __shared__ float red[128];
    __shared__ float hh[128];
    red[t] = x; __syncthreads();
    for (int off = 64; off > 0; off >>= 1) { if (t < off) red[t] += red[t+off]; __syncthreads(); }
    float mean = red[0] * (1.f/128.f); __syncthreads();
    float dx = x - mean;
    red[t] = dx*dx; __syncthreads();
    for (int off = 64; off > 0; off >>= 1) { if (t < off) red[t] += red[t+off]; __syncthreads(); }
    float var = red[0] * (1.f/128.f);
    hh[t] = dx * rsqrtf(var + LNEPS) * g[t] + b[t];
    __syncthreads();
    float acc = 0.f;
    for (int d = 0; d < 128; ++d) acc = fmaf(hh[d], Wq[d*128 + t], acc);
    qg[s*128 + t] = acc;
}

/* ====== attention tile: 64 pixels/block; softmax over slots; partial U,Ssum ====== */
#define STK 129
#define STQ 132
#define STT 36
__global__ __launch_bounds__(256) void k_attn(
    const float* __restrict__ kv, const float* __restrict__ qg,
    float* __restrict__ part)
{
    __shared__ float q_lds[NS*STQ];
    __shared__ float k_lds[64*STK];
    __shared__ float at[64*STT];
    int t   = threadIdx.x;
    int px0 = blockIdx.x * 64;
    #pragma unroll
    for (int r = 0; r < 16; ++r) {
        int id = t + 256*r;
        int s = id >> 7, d = id & 127;
        q_lds[s*STQ + d] = qg[id];
    }
    #pragma unroll
    for (int r = 0; r < 32; ++r) {
        int id = t + 256*r;
        int p = id >> 7, d = id & 127;
        k_lds[p*STK + d] = kv[(size_t)(px0+p)*256 + d];
    }
    __syncthreads();

    /* logits: wave w handles slot set {4u+w}, lane = pixel */
    int wv = t >> 6, p = t & 63;
    float acc[8];
    #pragma unroll
    for (int u = 0; u < 8; ++u) acc[u] = 0.f;
    for (int dc = 0; dc < 4; ++dc) {
        float kr[32];
        #pragma unroll
        for (int d = 0; d < 32; ++d) kr[d] = k_lds[p*STK + dc*32 + d];
        #pragma unroll
        for (int u = 0; u < 8; ++u) {
            int s = u*4 + wv;
            const float* qp = &q_lds[s*STQ + dc*32];
            #pragma unroll
            for (int ii = 0; ii < 8; ++ii) {
                float4 q4 = *(const float4*)(qp + 4*ii);
                acc[u] = fmaf(q4.x, kr[4*ii+0], acc[u]);
                acc[u] = fmaf(q4.y, kr[4*ii+1], acc[u]);
                acc[u] = fmaf(q4.z, kr[4*ii+2], acc[u]);
                acc[u] = fmaf(q4.w, kr[4*ii+3], acc[u]);
            }
        }
    }
    #pragma unroll
    for (int u = 0; u < 8; ++u) at[p*STT + u*4 + wv] = acc[u] * QSCALE;
    __syncthreads();

    /* softmax over slots, per pixel */
    if (t < 64) {
        float mx = -1e30f;
        #pragma unroll
        for (int s = 0; s < NS; ++s) mx = fmaxf(mx, at[t*STT + s]);
        float smv = 0.f;
        #pragma unroll
        for (int s = 0; s < NS; ++s) { float e = expf(at[t*STT + s] - mx); at[t*STT + s] = e; smv += e; }
        float inv = 1.f / smv;
        #pragma unroll
        for (int s = 0; s < NS; ++s) at[t*STT + s] *= inv;
    }
    __syncthreads();

    /* U[s][d] partial + Ssum[s] partial */
    int d = t & 127, sh = t >> 7;
    float u16[16];
    #pragma unroll
    for (int i = 0; i < 16; ++i) u16[i] = 0.f;
    const float* vbase = kv + (size_t)px0*256 + 128 + d;
    #pragma unroll 4
    for (int pp = 0; pp < 64; ++pp) {
        float vv = vbase[(size_t)pp*256];
        const float4* ap = (const float4*)&at[pp*STT + sh*16];
        #pragma unroll
        for (int gg = 0; gg < 4; ++gg) {
            float4 a4 = ap[gg];
            u16[4*gg+0] = fmaf(a4.x, vv, u16[4*gg+0]);
            u16[4*gg+1] = fmaf(a4.y, vv, u16[4*gg+1]);
            u16[4*gg+2] = fmaf(a4.z, vv, u16[4*gg+2]);
            u16[4*gg+3] = fmaf(a4.w, vv, u16[4*gg+3]);
        }
    }
    float* P = part + (size_t)blockIdx.x * 4128;
    #pragma unroll
    for (int g2 = 0; g2 < 16; ++g2) P[(sh*16 + g2)*128 + d] = u16[g2];
    if (t < 32) {
        float ss = 0.f;
        for (int pp = 0; pp < 64; ++pp) ss += at[pp*STT + t];
        P[4096 + t] = ss;
    }
}

/* ====== reduce partials, slot update, LN for MLP ====== */
__global__ __launch_bounds__(128) void k_update(
    const float* __restrict__ part, float* __restrict__ slots,
    float* __restrict__ hm, const float* __restrict__ g, const float* __restrict__ b)
{
    int s = blockIdx.x, t = threadIdx.x;
    float u = 0.f, ss = 0.f;
    for (int bb = 0; bb < 256; ++bb) {
        const float* P = part + (size_t)bb * 4128;
        u  += P[s*128 + t];
        ss += P[4096 + s];
    }
    float x = slots[s*128 + t] + u / (ss + ATEPS);
    __shared__ float red[128];
    red[t] = x; __syncthreads();
    for (int off = 64; off > 0; off >>= 1) { if (t < off) red[t] += red[t+off]; __syncthreads(); }
    float mean = red[0] * (1.f/128.f); __syncthreads();
    float dx = x - mean;
    red[t] = dx*dx; __syncthreads();
    for (int off = 64; off > 0; off >>= 1) { if (t < off) red[t] += red[t+off]; __syncthreads(); }
    float var = red[0] * (1.f/128.f);
    slots[s*128 + t] = x;
    hm[s*128 + t] = dx * rsqrtf(var + LNEPS) * g[t] + b[t];
}

/* ====== slot MLP residual: slots += relu(h@w1+b1)@w2+b2 ====== */
__global__ __launch_bounds__(256) void k_mlp(
    const float* __restrict__ hm, const float* __restrict__ w1, const float* __restrict__ b1,
    const float* __restrict__ w2, const float* __restrict__ b2, float* __restrict__ slots)
{
    int s = blockIdx.x, t = threadIdx.x;
    __shared__ float h[128], hid[256];
    if (t < 128) h[t] = hm[s*128 + t];
    __syncthreads();
    float a = b1[t];
    for (int d = 0; d < 128; ++d) a = fmaf(h[d], w1[d*256 + t], a);
    hid[t] = fmaxf(a, 0.f);
    __syncthreads();
    if (t < 128) {
        float o = b2[t];
        for (int j = 0; j < 256; ++j) o = fmaf(hid[j], w2[j*128 + t], o);
        slots[s*128 + t] += o;
    }
}

/* ====== objects = relu(slots@w1+b1)@w2+b2 ====== */
__global__ __launch_bounds__(256) void k_prop(
    const float* __restrict__ slots, const float* __restrict__ w1, const float* __restrict__ b1,
    const float* __restrict__ w2, const float* __restrict__ b2, float* __restrict__ objects)
{
    int s = blockIdx.x, t = threadIdx.x;
    __shared__ float h[128], hid[256];
    if (t < 128) h[t] = slots[s*128 + t];
    __syncthreads();
    float a = b1[t];
    for (int d = 0; d < 128; ++d) a = fmaf(h[d], w1[d*256 + t], a);
    hid[t] = fmaxf(a, 0.f);
    __syncthreads();
    if (t < 128) {
        float o = b2[t];
        for (int j = 0; j < 256; ++j) o = fmaf(hid[j], w2[j*128 + t], o);
        objects[s*128 + t] = o;
    }
}

/* ====== relations: per (i,j) pair MLP 256->128(relu)->64 ====== */
__global__ __launch_bounds__(128) void k_rel(
    const float* __restrict__ objects, const float* __restrict__ w1, const float* __restrict__ b1,
    const float* __restrict__ w2, const float* __restrict__ b2, float* __restrict__ rel_out)
{
    int pr = blockIdx.x; int i = pr >> 5, j = pr & 31; int t = threadIdx.x;
    __shared__ float pair[256], hid[128];
    pair[t]       = objects[i*128 + t];
    pair[128 + t] = objects[j*128 + t];
    __syncthreads();
    float a = b1[t];
    for (int c = 0; c < 256; ++c) a = fmaf(pair[c], w1[c*128 + t], a);
    hid[t] = fmaxf(a, 0.f);
    __syncthreads();
    if (t < 64) {
        float o = b2[t];
        for (int c = 0; c < 128; ++c) o = fmaf(hid[c], w2[c*64 + t], o);
        rel_out[(size_t)pr*64 + t] = o;
    }
}

/* ====== dynamics: next_objects into feat[0:4096] ====== */
__global__ __launch_bounds__(256) void k_dyn(
    const float* __restrict__ objects, const float* __restrict__ action,
    const float* __restrict__ w1, const float* __restrict__ b1,
    const float* __restrict__ w2, const float* __restrict__ b2,
    const float* __restrict__ w3, const float* __restrict__ b3,
    const float* __restrict__ gravity, float* __restrict__ feat)
{
    int s = blockIdx.x, t = threadIdx.x;
    __shared__ float inp[144], h1[256], h2[256];
    if (t < 128) inp[t] = objects[s*128 + t];
    else if (t < 144) inp[t] = action[t - 128];
    __syncthreads();
    float a = b1[t];
    for (int c = 0; c < 144; ++c) a = fmaf(inp[c], w1[c*256 + t], a);
    h1[t] = fmaxf(a, 0.f);
    __syncthreads();
    float a2 = b2[t];
    for (int c = 0; c < 256; ++c) a2 = fmaf(h1[c], w2[c*256 + t], a2);
    h2[t] = fmaxf(a2, 0.f);
    __syncthreads();
    if (t < 128) {
        float dlt = b3[t];
        for (int c = 0; c < 256; ++c) dlt = fmaf(h2[c], w3[c*128 + t], dlt);
        if (t < 3) dlt += gravity[t] * DTC;
        feat[s*128 + t] = objects[s*128 + t] + dlt * DTC;
    }
}

/* ====== renderer stage 1: feat @ rend_w1 partials (the 428 MB read) ====== */
__global__ __launch_bounds__(384) void k_rend1(
    const float* __restrict__ feat, const float* __restrict__ w1, float* __restrict__ p1)
{
    int b = blockIdx.x, t = threadIdx.x;
    float4 acc = make_float4(0.f, 0.f, 0.f, 0.f);
    int i0 = b * 68;
    #pragma unroll 4
    for (int r = 0; r < 68; ++r) {
        int i = i0 + r;
        float f = feat[i];
        float4 w = *(const float4*)(w1 + (size_t)i * 1536 + 4*t);
        acc.x = fmaf(f, w.x, acc.x);
        acc.y = fmaf(f, w.y, acc.y);
        acc.z = fmaf(f, w.z, acc.z);
        acc.w = fmaf(f, w.w, acc.w);
    }
    *(float4*)(p1 + (size_t)b * 1536 + 4*t) = acc;
}

/* ====== renderer stage 2: reduce + bias + relu -> h(1536) ====== */
__global__ __launch_bounds__(256) void k_rend2(
    const float* __restrict__ p1, const float* __restrict__ b1, float* __restrict__ h)
{
    int j = blockIdx.x * 256 + threadIdx.x;
    float a0 = 0.f, a1 = 0.f, a2 = 0.f, a3 = 0.f;
    #pragma unroll 4
    for (int bb = 0; bb < 1024; bb += 4) {
        a0 += p1[(size_t)(bb+0)*1536 + j];
        a1 += p1[(size_t)(bb+1)*1536 + j];
        a2 += p1[(size_t)(bb+2)*1536 + j];
        a3 += p1[(size_t)(bb+3)*1536 + j];
    }
    h[j] = fmaxf((a0+a1) + (a2+a3) + b1[j], 0.f);
}

/* ====== renderer stage 3: h @ rend_w2 partials ====== */
__global__ __launch_bounds__(256) void k_rend3(
    const float* __restrict__ h, const float* __restrict__ w2, float* __restrict__ p3)
{
    int bj = blockIdx.x, t = threadIdx.x;
    int j0 = bj * 32;
    float a0 = 0.f, a1 = 0.f, a2 = 0.f;
    #pragma unroll
    for (int j = 0; j < 32; ++j) {
        float hj = h[j0 + j];
        const float* w = w2 + (size_t)(j0 + j) * 768;
        a0 = fmaf(hj, w[t],       a0);
        a1 = fmaf(hj, w[t + 256], a1);
        a2 = fmaf(hj, w[t + 512], a2);
    }
    p3[(size_t)bj*768 + t]       = a0;
    p3[(size_t)bj*768 + t + 256] = a1;
    p3[(size_t)bj*768 + t + 512] = a2;
}

/* ====== renderer stage 4: reduce + bias -> out(768) ====== */
__global__ __launch_bounds__(256) void k_rend4(
    const float* __restrict__ p3, const float* __restrict__ b2, float* __restrict__ out)
{
    int m = blockIdx.x * 256 + threadIdx.x;
    float a = b2[m];
    #pragma unroll
    for (int bj = 0; bj < 48; ++bj) a += p3[(size_t)bj*768 + m];
    out[m] = a;
}

extern "C" void kernel_launch(void* const* d_in, const int* in_sizes, int n_in,
                              void* d_out, int out_size, void* d_ws, size_t ws_size,
                              hipStream_t stream) {
    (void)in_sizes; (void)n_in; (void)out_size; (void)ws_size;
    const float* obs      = (const float*)d_in[0];
    const float* action   = (const float*)d_in[1];
    const float* noise    = (const float*)d_in[2];
    const float* mu       = (const float*)d_in[3];
    const float* lsig     = (const float*)d_in[4];
    const float* ln_in_g  = (const float*)d_in[5];
    const float* ln_in_b  = (const float*)d_in[6];
    const float* ln_s_g   = (const float*)d_in[7];
    const float* ln_s_b   = (const float*)d_in[8];
    const float* ln_m_g   = (const float*)d_in[9];
    const float* ln_m_b   = (const float*)d_in[10];
    const float* Wq       = (const float*)d_in[11];
    const float* Wk       = (const float*)d_in[12];
    const float* Wv       = (const float*)d_in[13];
    const float* mlp_w1   = (const float*)d_in[14];
    const float* mlp_b1   = (const float*)d_in[15];
    const float* mlp_w2   = (const float*)d_in[16];
    const float* mlp_b2   = (const float*)d_in[17];
    const float* prop_w1  = (const float*)d_in[18];
    const float* prop_b1  = (const float*)d_in[19];
    const float* prop_w2  = (const float*)d_in[20];
    const float* prop_b2  = (const float*)d_in[21];
    const float* rel_w1   = (const float*)d_in[22];
    const float* rel_b1   = (const float*)d_in[23];
    const float* rel_w2   = (const float*)d_in[24];
    const float* rel_b2   = (const float*)d_in[25];
    const float* dyn_w1   = (const float*)d_in[26];
    const float* dyn_b1   = (const float*)d_in[27];
    const float* dyn_w2   = (const float*)d_in[28];
    const float* dyn_b2   = (const float*)d_in[29];
    const float* dyn_w3   = (const float*)d_in[30];
    const float* dyn_b3   = (const float*)d_in[31];
    const float* gravity  = (const float*)d_in[32];
    const float* rend_w1  = (const float*)d_in[33];
    const float* rend_b1  = (const float*)d_in[34];
    const float* rend_w2  = (const float*)d_in[35];
    const float* rend_b2  = (const float*)d_in[36];
    float* out = (float*)d_out;

    float* w      = (float*)d_ws;
    float* stats  = w + OFF_STATS;
    float* kv     = w + OFF_KV;
    float* slots  = w + OFF_SLOTS;
    float* qg     = w + OFF_Q;
    float* hm     = w + OFF_H;
    float* apart  = w + OFF_APART;
    float* objs   = w + OFF_OBJ;
    float* feat   = w + OFF_FEAT;             /* [next_objects(4096) | relations(65536)] */
    float* relout = feat + 4096;
    float* p1     = w + OFF_P1;
    float* hrend  = w + OFF_HREND;
    float* p3     = w + OFF_P3;

    k_stats<<<4096, 256, 0, stream>>>(obs, stats);
    k_kv<<<dim3(128, 2), 256, 0, stream>>>(obs, stats, ln_in_g, ln_in_b, Wk, Wv, kv);
    k_slots_init<<<16, 256, 0, stream>>>(mu, lsig, noise, slots);

    for (int it = 0; it < 3; ++it) {
        k_q<<<32, 128, 0, stream>>>(slots, Wq, ln_s_g, ln_s_b, qg);
        k_attn<<<256, 256, 0, stream>>>(kv, qg, apart);
        k_update<<<32, 128, 0, stream>>>(apart, slots, hm, ln_m_g, ln_m_b);
        k_mlp<<<32, 256, 0, stream>>>(hm, mlp_w1, mlp_b1, mlp_w2, mlp_b2, slots);
    }

    k_prop<<<32, 256, 0, stream>>>(slots, prop_w1, prop_b1, prop_w2, prop_b2, objs);
    k_rel<<<1024, 128, 0, stream>>>(objs, rel_w1, rel_b1, rel_w2, rel_b2, relout);
    k_dyn<<<32, 256, 0, stream>>>(objs, action, dyn_w1, dyn_b1, dyn_w2, dyn_b2,
                                  dyn_w3, dyn_b3, gravity, feat);

    k_rend1<<<1024, 384, 0, stream>>>(feat, rend_w1, p1);
    k_rend2<<<6, 256, 0, stream>>>(p1, rend_b1, hrend);
    k_rend3<<<48, 256, 0, stream>>>(hrend, rend_w2, p3);
    k_rend4<<<3, 256, 0, stream>>>(p3, rend_b2, out);
}